// Round 14
// baseline (562.161 us; speedup 1.0000x reference)
//
#include <hip/hip_runtime.h>
#include <math.h>

#define T_STEPS 50
#define D_IN    620
#define N1      200
#define N2      100
#define N3      11
#define BATCH   4096

typedef short bf16x8 __attribute__((ext_vector_type(8)));
typedef float f32x4  __attribute__((ext_vector_type(4)));

__device__ __constant__ float KV[10] = {
    -0.0033689735f, -0.0091578194f, -0.0248935342f, -0.0676676416f, -0.1839397206f,
     1.0f,           0.6065306597f,  0.3678794412f,  0.2231301601f,  0.1353352832f };

#define RHO    0.60653066f     /* e^-1/2 */
#define RHO5   0.0820849986f   /* e^-5/2 */
#define RHO10  0.0067379470f   /* e^-5   */
#define KV0    (-0.0033689735f)
#define C1     (-0.0091578194f)
#define C2     (-0.0248935342f)
#define C3     (-0.0676676416f)
#define C4     (-0.1839397206f)

__device__ __forceinline__ float sigm10(float x) { return 1.0f / (1.0f + __expf(-10.0f * x)); }
__device__ __forceinline__ float swishf(float v) { return v / (1.0f + __expf(-10.0f * v)); }

__device__ __forceinline__ void split2(float x, unsigned short& hi, unsigned short& lo) {
    unsigned u = __float_as_uint(x);
    hi = (unsigned short)(u >> 16);
    float rem = x - __uint_as_float(u & 0xFFFF0000u);   // exact
    lo = (unsigned short)(__float_as_uint(rem) >> 16);
}

// ---------------------------------------------------------------------------
// Merged prep: W1 -> 20 k-tiles of [p][208][32] bf16 (granule^=( (n>>1)&3 ))
// and W2 -> per-wave MFMA B-fragments.  One dispatch.
// ---------------------------------------------------------------------------
__global__ void prep_w(const float* __restrict__ W1, const float* __restrict__ W2,
                       unsigned short* __restrict__ W1pre, unsigned short* __restrict__ W2pre2) {
    int i = blockIdx.x * 256 + threadIdx.x;
    if (i < 266240) {                      // W1 path: 20*2*208*32
        int kk = i & 31;
        int t1 = i >> 5;
        int n  = t1 % 208;
        int t2 = t1 / 208;                 // kt*2 + p
        int p  = t2 & 1;
        int kt = t2 >> 1;
        int k  = kt * 32 + kk;
        float w = (n < N1 && k < D_IN) ? W1[n * D_IN + k] : 0.0f;
        unsigned short hi, lo; split2(w, hi, lo);
        int gsw = (kk >> 3) ^ ((n >> 1) & 3);
        int idx = kt * 13312 + p * 6656 + n * 32 + gsw * 8 + (kk & 7);
        W1pre[idx] = p ? lo : hi;
    } else {
        int i2 = i - 266240;               // W2 path: 57344
        if (i2 < 57344) {
            int e  = i2 & 7;
            int r  = i2 >> 3;
            int l  = r & 63;
            int r2 = r >> 6;
            int p  = r2 & 1;
            int r3 = r2 >> 1;
            int ks = r3 % 7;
            int wv = r3 / 7;
            int n  = wv * 16 + (l & 15);
            int k  = ks * 32 + (l >> 4) * 8 + e;
            float v = (n < N2 && k < N1) ? W2[n * N1 + k] : 0.0f;
            unsigned short hi, lo; split2(v, hi, lo);
            W2pre2[i2] = p ? lo : hi;
        }
    }
}

// ---------------------------------------------------------------------------
// MFMA GEMM1 v5c: round-9 v5b + UNIFORM stageB (4 load-instrs per wave:
// 4th chunk issued by lanes 0..15 of EVERY wave, consecutive chunks so the
// wave-uniform-base + lane*16 LDS rule holds) + exact vmcnt counts
// (prologue 8, steady 6, kt==18 full drain).  Removes waves-0/1 overwait.
// ---------------------------------------------------------------------------
__global__ __launch_bounds__(512, 4) void gemm1_mfma(const float* __restrict__ x,
                                                     const unsigned short* __restrict__ W1pre,
                                                     float* __restrict__ h1) {
    __shared__ unsigned short Bs[3][13312];           // 79872 B

    const int tid = threadIdx.x;
    const int w   = tid >> 6;
    const int l   = tid & 63;
    const int j   = l >> 4;
    const int r16 = l & 15;
    const long row0 = (long)blockIdx.x * 128;
    const float* arow = x + (row0 + w * 16 + r16) * D_IN;

    f32x4 acc[13];
#pragma unroll
    for (int nt = 0; nt < 13; ++nt) acc[nt] = (f32x4){0.f, 0.f, 0.f, 0.f};

    auto stageB = [&](int kt, int bb) {
        const unsigned short* src = W1pre + kt * 13312;
        unsigned short* dst = &Bs[bb][0];
#pragma unroll
        for (int it = 0; it < 3; ++it) {
            int ch = it * 512 + tid;                  // 16B chunk index
            __builtin_amdgcn_global_load_lds(
                (const __attribute__((address_space(1))) unsigned int*)(src + ch * 8),
                (__attribute__((address_space(3))) unsigned int*)(dst + ch * 8), 16, 0, 0);
        }
        // 4th chunk: lanes 0..15 of EVERY wave -> uniform vmcnt (+1 per wave);
        // per-wave chunks consecutive: first active lane gives the base,
        // hardware writes base + lane*16 (matches ch = base + lane).
        if (l < 16) {
            int ch = 1536 + w * 16 + l;
            __builtin_amdgcn_global_load_lds(
                (const __attribute__((address_space(1))) unsigned int*)(src + ch * 8),
                (__attribute__((address_space(3))) unsigned int*)(dst + ch * 8), 16, 0, 0);
        }
    };

    auto loadA = [&](int kt, float* av) {
        const float* p = arow + kt * 32 + j * 8;
        const float4 u0 = *(const float4*)p;
        const float4 u1 = *(const float4*)(p + 4);
        av[0] = u0.x; av[1] = u0.y; av[2] = u0.z; av[3] = u0.w;
        av[4] = u1.x; av[5] = u1.y; av[6] = u1.z; av[7] = u1.w;
    };
    auto loadAtail = [&](float* av) {
        if (j == 0) {
            const float4 u0 = *(const float4*)(arow + 608);
            const float4 u1 = *(const float4*)(arow + 612);
            av[0] = u0.x; av[1] = u0.y; av[2] = u0.z; av[3] = u0.w;
            av[4] = u1.x; av[5] = u1.y; av[6] = u1.z; av[7] = u1.w;
        } else if (j == 1) {
            const float4 u0 = *(const float4*)(arow + 616);
            av[0] = u0.x; av[1] = u0.y; av[2] = u0.z; av[3] = u0.w;
            av[4] = 0.f; av[5] = 0.f; av[6] = 0.f; av[7] = 0.f;
        } else {
#pragma unroll
            for (int e = 0; e < 8; ++e) av[e] = 0.f;
        }
    };

    float av[2][8];
    stageB(0, 0);           // 4 instrs/wave
    stageB(1, 1);           // 4
    loadA(0, av[0]);        // 2
    loadA(1, av[1]);        // 2
    // drain stageB(0): newer = 4 + 2 + 2 = 8 (uniform, exact)
    asm volatile("s_waitcnt vmcnt(8)" ::: "memory");
    asm volatile("s_barrier" ::: "memory");

#pragma unroll 1
    for (int kt = 0; kt < 20; ++kt) {
        bf16x8 ah, al;
#pragma unroll
        for (int e = 0; e < 8; ++e) {
            unsigned short hi, lo; split2(av[kt & 1][e], hi, lo);
            ah[e] = (short)hi; al[e] = (short)lo;
        }
        if (kt < 18) {
            if (kt + 2 == 19) loadAtail(av[kt & 1]); else loadA(kt + 2, av[kt & 1]);
            stageB(kt + 2, (kt + 2) % 3);
        }
        const unsigned short* B = &Bs[kt % 3][0];
#pragma unroll
        for (int nt = 0; nt < 13; ++nt) {
            const int n  = nt * 16 + r16;
            const int gs = j ^ ((n >> 1) & 3);
            const bf16x8 bh = *(const bf16x8*)(B + n * 32 + gs * 8);
            const bf16x8 bl = *(const bf16x8*)(B + 6656 + n * 32 + gs * 8);
            acc[nt] = __builtin_amdgcn_mfma_f32_16x16x32_bf16(ah, bh, acc[nt], 0, 0, 0);
            acc[nt] = __builtin_amdgcn_mfma_f32_16x16x32_bf16(ah, bl, acc[nt], 0, 0, 0);
            acc[nt] = __builtin_amdgcn_mfma_f32_16x16x32_bf16(al, bh, acc[nt], 0, 0, 0);
        }
        // steady: drain B(kt+1); newer = A(kt+2) 2 + B(kt+2) 4 = 6 (exact, uniform)
        if (kt < 18) {
            asm volatile("s_waitcnt vmcnt(6)" ::: "memory");
            asm volatile("s_barrier" ::: "memory");
        } else if (kt == 18) {
            asm volatile("s_waitcnt vmcnt(0)" ::: "memory");
            asm volatile("s_barrier" ::: "memory");
        }
    }

#pragma unroll
    for (int nt = 0; nt < 13; ++nt) {
        const int gcol = nt * 16 + r16;
        if (gcol < N1) {
            const long grow0 = row0 + w * 16 + j * 4;
#pragma unroll
            for (int q = 0; q < 4; ++q)
                h1[(grow0 + q) * N1 + gcol] = swishf(acc[nt][q]);
        }
    }
}

// ---------------------------------------------------------------------------
// In-place causal conv (round-9 known-good; ~HBM-bound)
// ---------------------------------------------------------------------------
__global__ __launch_bounds__(256) void conv_k(float* __restrict__ buf) {
    __shared__ float h1s[T_STEPS * N1];
    const int b = blockIdx.x, tid = threadIdx.x;
    float* p = buf + (size_t)b * (T_STEPS * N1);
    for (int i = tid; i < T_STEPS * N1 / 4; i += 256)
        ((float4*)h1s)[i] = ((const float4*)p)[i];
    __syncthreads();
    for (int i = tid; i < T_STEPS * N1; i += 256) {
        int t = i / N1, n = i - t * N1;
        float s = 0.0f;
#pragma unroll
        for (int k = 0; k < 10; ++k)
            if (k <= t) s = fmaf(KV[k], h1s[(t - k) * N1 + n], s);
        p[i] = s;
    }
}

// ---------------------------------------------------------------------------
// Recurrent scan v5c: round-9 scan5 + P2 MFMA accumulation split into 4
// chains (max depth 6 vs 11) to cut dependent-MFMA latency in the serial
// per-step path.  +8 VGPR; everything else identical.
// ---------------------------------------------------------------------------
__global__ __launch_bounds__(512, 2) void snn_scan5(const float* __restrict__ syn2,
                                                    const unsigned short* __restrict__ W2pre2,
                                                    const float* __restrict__ W3,
                                                    float* __restrict__ out) {
    __shared__ __align__(16) unsigned short s2A[8192];   // [p][16][256]; rows 8..15 stay 0
    __shared__ __align__(16) float h2buf[8][132];
    __shared__ __align__(16) float s3buf[8][104];
    __shared__ __align__(16) float W3s[N3 * N2];
    __shared__ __align__(16) float pbuf[8][4][12];

    const int tid = threadIdx.x;
    const int wv  = tid >> 6;
    const int l   = tid & 63;
    const int m16 = l & 15;
    const int j2  = l >> 4;
    const int g   = wv;
    const int c   = l;
    const long b  = (long)blockIdx.x * 8 + g;

    for (int i = tid; i < N3 * N2; i += 512) W3s[i] = W3[i];
    for (int i = tid; i < 8192; i += 512) s2A[i] = 0;

    bf16x8 bh[7], bl[7];
    {
        const unsigned short* wp = W2pre2 + wv * 7168 + l * 8;
#pragma unroll
        for (int ks = 0; ks < 7; ++ks) {
            bh[ks] = *(const bf16x8*)(wp + ks * 1024);
            bl[ks] = *(const bf16x8*)(wp + ks * 1024 + 512);
        }
    }

    const int NL2 = (c < 8)  ? 4 : 3;
    const int NL3 = (c < 36) ? 2 : 1;
    const int o4  = c % 11;
    const int p4  = c / 11;
    const int kbeg = (p4 == 0) ? 0 : (4 + 24 * p4);
    const int nf4  = (p4 == 0) ? 7 : 6;

    float sl2h[10][4] = {}; float Ssl2[4] = {};
    float h2h[10][2]  = {}; float Dd3[2]  = {};
    float sl3h[10][2] = {}; float Ssl3[2] = {};
    float h3h[10]     = {}; float Dd4 = 0.f;
    float sl4h[10]    = {}; float Ssl4 = 0.f;
    float accum       = 0.0f;

    const float* syn2b = syn2 + b * (T_STEPS * N1);
    float syn_nxt[4];
#pragma unroll
    for (int jj = 0; jj < 4; ++jj) syn_nxt[jj] = (jj < NL2) ? syn2b[c + 64 * jj] : 0.0f;

    __syncthreads();

#pragma unroll 1
    for (int tb = 0; tb < T_STEPS; tb += 10) {
#pragma unroll
        for (int u = 0; u < 10; ++u) {
            const int t   = tb + u;
            const int um1 = (u + 9) % 10;
            const int um2 = (u + 8) % 10;
            const int um3 = (u + 7) % 10;
            const int um4 = (u + 6) % 10;
            const int um5 = (u + 5) % 10;

            float syn_cur[4];
#pragma unroll
            for (int jj = 0; jj < 4; ++jj) syn_cur[jj] = syn_nxt[jj];
            if (t + 1 < T_STEPS) {
#pragma unroll
                for (int jj = 0; jj < 4; ++jj)
                    if (jj < NL2) syn_nxt[jj] = syn2b[(t + 1) * N1 + c + 64 * jj];
            }

            // ---- P1: layer-2 (exact KS recurrence) ----
#pragma unroll
            for (int jj = 0; jj < 4; ++jj) {
                if (jj < NL2) {
                    const int n = c + 64 * jj;
                    const float slp = sl2h[um1][jj];
                    const float slo = sl2h[u][jj];          // lag 10
                    Ssl2[jj] = RHO * (Ssl2[jj] + slp) - RHO10 * slo;
                    const float mem2 = syn_cur[jj] - Ssl2[jj];
                    const float s2   = sigm10(mem2 - 0.5f);
                    sl2h[u][jj] = s2 * mem2;
                    unsigned short hi, lo; split2(s2, hi, lo);
                    const int off = g * 256 + (((n >> 3) ^ (g & 7)) * 8) + (n & 7);
                    s2A[off]        = hi;
                    s2A[4096 + off] = lo;
                }
            }
            __syncthreads();                               // bar 1

            // ---- P2: MFMA GEMM2 (4 accumulator chains, max depth 6) ----
            {
                f32x4 a0 = (f32x4){0.f, 0.f, 0.f, 0.f};
                f32x4 a1 = (f32x4){0.f, 0.f, 0.f, 0.f};
                f32x4 a2 = (f32x4){0.f, 0.f, 0.f, 0.f};
                f32x4 a3 = (f32x4){0.f, 0.f, 0.f, 0.f};
                const int swz = m16 & 7;
#pragma unroll
                for (int ks = 0; ks < 7; ++ks) {
                    const int gr = (4 * ks + j2) ^ swz;
                    const bf16x8 ahv = *(const bf16x8*)&s2A[m16 * 256 + gr * 8];
                    const bf16x8 alv = *(const bf16x8*)&s2A[4096 + m16 * 256 + gr * 8];
                    switch ((3 * ks + 0) & 3) {
                        case 0: a0 = __builtin_amdgcn_mfma_f32_16x16x32_bf16(ahv, bh[ks], a0, 0, 0, 0); break;
                        case 1: a1 = __builtin_amdgcn_mfma_f32_16x16x32_bf16(ahv, bh[ks], a1, 0, 0, 0); break;
                        case 2: a2 = __builtin_amdgcn_mfma_f32_16x16x32_bf16(ahv, bh[ks], a2, 0, 0, 0); break;
                        default: a3 = __builtin_amdgcn_mfma_f32_16x16x32_bf16(ahv, bh[ks], a3, 0, 0, 0); break;
                    }
                    switch ((3 * ks + 1) & 3) {
                        case 0: a0 = __builtin_amdgcn_mfma_f32_16x16x32_bf16(alv, bh[ks], a0, 0, 0, 0); break;
                        case 1: a1 = __builtin_amdgcn_mfma_f32_16x16x32_bf16(alv, bh[ks], a1, 0, 0, 0); break;
                        case 2: a2 = __builtin_amdgcn_mfma_f32_16x16x32_bf16(alv, bh[ks], a2, 0, 0, 0); break;
                        default: a3 = __builtin_amdgcn_mfma_f32_16x16x32_bf16(alv, bh[ks], a3, 0, 0, 0); break;
                    }
                    switch ((3 * ks + 2) & 3) {
                        case 0: a0 = __builtin_amdgcn_mfma_f32_16x16x32_bf16(ahv, bl[ks], a0, 0, 0, 0); break;
                        case 1: a1 = __builtin_amdgcn_mfma_f32_16x16x32_bf16(ahv, bl[ks], a1, 0, 0, 0); break;
                        case 2: a2 = __builtin_amdgcn_mfma_f32_16x16x32_bf16(ahv, bl[ks], a2, 0, 0, 0); break;
                        default: a3 = __builtin_amdgcn_mfma_f32_16x16x32_bf16(ahv, bl[ks], a3, 0, 0, 0); break;
                    }
                }
                const f32x4 a = (a0 + a1) + (a2 + a3);
                if (j2 < 2) {
#pragma unroll
                    for (int q = 0; q < 4; ++q)
                        h2buf[j2 * 4 + q][wv * 16 + m16] = swishf(a[q]);
                }
            }
            __syncthreads();                               // bar 2

            // ---- P3: layer-3 ----
#pragma unroll
            for (int jj = 0; jj < 2; ++jj) {
                if (jj < NL3) {
                    const int m = c + 64 * jj;
                    const float hm = h2buf[g][m];
                    float gneg = C1 * h2h[um1][jj];
                    gneg = fmaf(C2, h2h[um2][jj], gneg);
                    gneg = fmaf(C3, h2h[um3][jj], gneg);
                    gneg = fmaf(C4, h2h[um4][jj], gneg);
                    Dd3[jj] = fmaf(RHO, Dd3[jj], h2h[um5][jj]);
                    Dd3[jj] = fmaf(-RHO5, h2h[u][jj], Dd3[jj]);
                    Ssl3[jj] = RHO * (Ssl3[jj] + sl3h[um1][jj]) - RHO10 * sl3h[u][jj];
                    const float mem3 = fmaf(KV0, hm, gneg) + Dd3[jj] - Ssl3[jj];
                    const float s3   = sigm10(mem3 - 0.5f);
                    sl3h[u][jj] = s3 * mem3;
                    h2h[u][jj]  = hm;
                    s3buf[g][m] = s3;
                }
            }
            asm volatile("s_waitcnt lgkmcnt(0)" ::: "memory");
            __builtin_amdgcn_sched_barrier(0);

            // ---- P4: GEMM3 partials (44 lanes) ----
            if (c < 44) {
                float part = 0.0f;
#pragma unroll
                for (int i = 0; i < 7; ++i) {
                    if (i < nf4) {
                        const float4 sv  = *(const float4*)&s3buf[g][kbeg + 4 * i];
                        const float4 wv4 = *(const float4*)&W3s[o4 * N2 + kbeg + 4 * i];
                        part = fmaf(sv.x, wv4.x, part);
                        part = fmaf(sv.y, wv4.y, part);
                        part = fmaf(sv.z, wv4.z, part);
                        part = fmaf(sv.w, wv4.w, part);
                    }
                }
                pbuf[g][p4][o4] = part;
            }
            asm volatile("s_waitcnt lgkmcnt(0)" ::: "memory");
            __builtin_amdgcn_sched_barrier(0);

            // ---- P5: layer-4 (11 lanes) ----
            if (c < N3) {
                const float a4 = pbuf[g][0][c] + pbuf[g][1][c] + pbuf[g][2][c] + pbuf[g][3][c];
                const float h3 = swishf(a4);
                float gneg = C1 * h3h[um1];
                gneg = fmaf(C2, h3h[um2], gneg);
                gneg = fmaf(C3, h3h[um3], gneg);
                gneg = fmaf(C4, h3h[um4], gneg);
                Dd4 = fmaf(RHO, Dd4, h3h[um5]);
                Dd4 = fmaf(-RHO5, h3h[u], Dd4);
                Ssl4 = RHO * (Ssl4 + sl4h[um1]) - RHO10 * sl4h[u];
                const float mem4 = fmaf(KV0, h3, gneg) + Dd4 - Ssl4;
                const float s4   = sigm10(mem4 - 0.5f);
                sl4h[u] = s4 * mem4;
                h3h[u]  = h3;
                accum += s4;
            }
        }
    }

    if (c < N3) out[b * N3 + c] = accum * 0.02f;
}

// ---------------------------------------------------------------------------
extern "C" void kernel_launch(void* const* d_in, const int* in_sizes, int n_in,
                              void* d_out, int out_size, void* d_ws, size_t ws_size,
                              hipStream_t stream) {
    const float* x  = (const float*)d_in[0];
    const float* W1 = (const float*)d_in[1];
    const float* W2 = (const float*)d_in[2];
    const float* W3 = (const float*)d_in[3];
    float* out = (float*)d_out;

    float* buf = (float*)d_ws;                                   // h1 -> syn2 in place
    unsigned short* W1pre  = (unsigned short*)(buf + (size_t)BATCH * T_STEPS * N1);
    unsigned short* W2pre2 = W1pre + 266240;

    prep_w<<<1264, 256, 0, stream>>>(W1, W2, W1pre, W2pre2);
    gemm1_mfma<<<1600, 512, 0, stream>>>(x, W1pre, buf);
    conv_k<<<BATCH, 256, 0, stream>>>(buf);
    snn_scan5<<<BATCH / 8, 512, 0, stream>>>(buf, W2pre2, W3, out);
}

// Round 15
// 528.071 us; speedup vs baseline: 1.0646x; 1.0646x over previous
//
#include <hip/hip_runtime.h>
#include <math.h>

#define T_STEPS 50
#define D_IN    620
#define N1      200
#define N2      100
#define N3      11
#define BATCH   4096

typedef short bf16x8 __attribute__((ext_vector_type(8)));
typedef float f32x4  __attribute__((ext_vector_type(4)));

__device__ __constant__ float KV[10] = {
    -0.0033689735f, -0.0091578194f, -0.0248935342f, -0.0676676416f, -0.1839397206f,
     1.0f,           0.6065306597f,  0.3678794412f,  0.2231301601f,  0.1353352832f };

#define RHO    0.60653066f     /* e^-1/2 */
#define RHO5   0.0820849986f   /* e^-5/2 */
#define RHO10  0.0067379470f   /* e^-5   */
#define KV0    (-0.0033689735f)
#define C1     (-0.0091578194f)
#define C2     (-0.0248935342f)
#define C3     (-0.0676676416f)
#define C4     (-0.1839397206f)

__device__ __forceinline__ float sigm10(float x) { return 1.0f / (1.0f + __expf(-10.0f * x)); }
__device__ __forceinline__ float swishf(float v) { return v / (1.0f + __expf(-10.0f * v)); }

__device__ __forceinline__ void split2(float x, unsigned short& hi, unsigned short& lo) {
    unsigned u = __float_as_uint(x);
    hi = (unsigned short)(u >> 16);
    float rem = x - __uint_as_float(u & 0xFFFF0000u);   // exact
    lo = (unsigned short)(__float_as_uint(rem) >> 16);
}

// ---------------------------------------------------------------------------
// Merged prep (single dispatch): W1 -> 20 k-tiles [p][208][32] bf16
// (granule^=( (n>>1)&3 )); W2 -> per-wave MFMA B-fragments.
// ---------------------------------------------------------------------------
__global__ void prep_w(const float* __restrict__ W1, const float* __restrict__ W2,
                       unsigned short* __restrict__ W1pre, unsigned short* __restrict__ W2pre2) {
    int i = blockIdx.x * 256 + threadIdx.x;
    if (i < 266240) {                      // W1 path: 20*2*208*32
        int kk = i & 31;
        int t1 = i >> 5;
        int n  = t1 % 208;
        int t2 = t1 / 208;                 // kt*2 + p
        int p  = t2 & 1;
        int kt = t2 >> 1;
        int k  = kt * 32 + kk;
        float w = (n < N1 && k < D_IN) ? W1[n * D_IN + k] : 0.0f;
        unsigned short hi, lo; split2(w, hi, lo);
        int gsw = (kk >> 3) ^ ((n >> 1) & 3);
        int idx = kt * 13312 + p * 6656 + n * 32 + gsw * 8 + (kk & 7);
        W1pre[idx] = p ? lo : hi;
    } else {
        int i2 = i - 266240;               // W2 path: 57344
        if (i2 < 57344) {
            int e  = i2 & 7;
            int r  = i2 >> 3;
            int l  = r & 63;
            int r2 = r >> 6;
            int p  = r2 & 1;
            int r3 = r2 >> 1;
            int ks = r3 % 7;
            int wv = r3 / 7;
            int n  = wv * 16 + (l & 15);
            int k  = ks * 32 + (l >> 4) * 8 + e;
            float v = (n < N2 && k < N1) ? W2[n * N1 + k] : 0.0f;
            unsigned short hi, lo; split2(v, hi, lo);
            W2pre2[i2] = p ? lo : hi;
        }
    }
}

// ---------------------------------------------------------------------------
// MFMA GEMM1 v5b (round-9 exact, best-known): BM=128 (8 waves x M=16),
// BN=208, BK=32, 3-pass bf16.  3-buffer LDS, stageB 2 ahead, counted vmcnt
// (steady 5, full drain at kt==18 to cover loadAtail's divergent queue).
// ---------------------------------------------------------------------------
__global__ __launch_bounds__(512, 4) void gemm1_mfma(const float* __restrict__ x,
                                                     const unsigned short* __restrict__ W1pre,
                                                     float* __restrict__ h1) {
    __shared__ unsigned short Bs[3][13312];           // 79872 B

    const int tid = threadIdx.x;
    const int w   = tid >> 6;
    const int l   = tid & 63;
    const int j   = l >> 4;
    const int r16 = l & 15;
    const long row0 = (long)blockIdx.x * 128;
    const float* arow = x + (row0 + w * 16 + r16) * D_IN;

    f32x4 acc[13];
#pragma unroll
    for (int nt = 0; nt < 13; ++nt) acc[nt] = (f32x4){0.f, 0.f, 0.f, 0.f};

    auto stageB = [&](int kt, int bb) {
        const unsigned short* src = W1pre + kt * 13312;
        unsigned short* dst = &Bs[bb][0];
#pragma unroll
        for (int it = 0; it < 3; ++it) {
            int ch = it * 512 + tid;                  // 16B chunk index
            __builtin_amdgcn_global_load_lds(
                (const __attribute__((address_space(1))) unsigned int*)(src + ch * 8),
                (__attribute__((address_space(3))) unsigned int*)(dst + ch * 8), 16, 0, 0);
        }
        if (tid < 128) {
            int ch = 1536 + tid;
            __builtin_amdgcn_global_load_lds(
                (const __attribute__((address_space(1))) unsigned int*)(src + ch * 8),
                (__attribute__((address_space(3))) unsigned int*)(dst + ch * 8), 16, 0, 0);
        }
    };

    auto loadA = [&](int kt, float* av) {
        const float* p = arow + kt * 32 + j * 8;
        const float4 u0 = *(const float4*)p;
        const float4 u1 = *(const float4*)(p + 4);
        av[0] = u0.x; av[1] = u0.y; av[2] = u0.z; av[3] = u0.w;
        av[4] = u1.x; av[5] = u1.y; av[6] = u1.z; av[7] = u1.w;
    };
    auto loadAtail = [&](float* av) {
        if (j == 0) {
            const float4 u0 = *(const float4*)(arow + 608);
            const float4 u1 = *(const float4*)(arow + 612);
            av[0] = u0.x; av[1] = u0.y; av[2] = u0.z; av[3] = u0.w;
            av[4] = u1.x; av[5] = u1.y; av[6] = u1.z; av[7] = u1.w;
        } else if (j == 1) {
            const float4 u0 = *(const float4*)(arow + 616);
            av[0] = u0.x; av[1] = u0.y; av[2] = u0.z; av[3] = u0.w;
            av[4] = 0.f; av[5] = 0.f; av[6] = 0.f; av[7] = 0.f;
        } else {
#pragma unroll
            for (int e = 0; e < 8; ++e) av[e] = 0.f;
        }
    };

    float av[2][8];
    stageB(0, 0);
    stageB(1, 1);
    loadA(0, av[0]);
    loadA(1, av[1]);
    asm volatile("s_waitcnt vmcnt(7)" ::: "memory");
    asm volatile("s_barrier" ::: "memory");

#pragma unroll 1
    for (int kt = 0; kt < 20; ++kt) {
        bf16x8 ah, al;
#pragma unroll
        for (int e = 0; e < 8; ++e) {
            unsigned short hi, lo; split2(av[kt & 1][e], hi, lo);
            ah[e] = (short)hi; al[e] = (short)lo;
        }
        if (kt < 18) {
            if (kt + 2 == 19) loadAtail(av[kt & 1]); else loadA(kt + 2, av[kt & 1]);
            stageB(kt + 2, (kt + 2) % 3);
        }
        const unsigned short* B = &Bs[kt % 3][0];
#pragma unroll
        for (int nt = 0; nt < 13; ++nt) {
            const int n  = nt * 16 + r16;
            const int gs = j ^ ((n >> 1) & 3);
            const bf16x8 bh = *(const bf16x8*)(B + n * 32 + gs * 8);
            const bf16x8 bl = *(const bf16x8*)(B + 6656 + n * 32 + gs * 8);
            acc[nt] = __builtin_amdgcn_mfma_f32_16x16x32_bf16(ah, bh, acc[nt], 0, 0, 0);
            acc[nt] = __builtin_amdgcn_mfma_f32_16x16x32_bf16(ah, bl, acc[nt], 0, 0, 0);
            acc[nt] = __builtin_amdgcn_mfma_f32_16x16x32_bf16(al, bh, acc[nt], 0, 0, 0);
        }
        if (kt < 18) {
            asm volatile("s_waitcnt vmcnt(5)" ::: "memory");
            asm volatile("s_barrier" ::: "memory");
        } else if (kt == 18) {
            asm volatile("s_waitcnt vmcnt(0)" ::: "memory");
            asm volatile("s_barrier" ::: "memory");
        }
    }

#pragma unroll
    for (int nt = 0; nt < 13; ++nt) {
        const int gcol = nt * 16 + r16;
        if (gcol < N1) {
            const long grow0 = row0 + w * 16 + j * 4;
#pragma unroll
            for (int q = 0; q < 4; ++q)
                h1[(grow0 + q) * N1 + gcol] = swishf(acc[nt][q]);
        }
    }
}

// ---------------------------------------------------------------------------
// In-place causal conv (round-9 exact; at its 328MB HBM roofline ~52-60us)
// ---------------------------------------------------------------------------
__global__ __launch_bounds__(256) void conv_k(float* __restrict__ buf) {
    __shared__ float h1s[T_STEPS * N1];
    const int b = blockIdx.x, tid = threadIdx.x;
    float* p = buf + (size_t)b * (T_STEPS * N1);
    for (int i = tid; i < T_STEPS * N1 / 4; i += 256)
        ((float4*)h1s)[i] = ((const float4*)p)[i];
    __syncthreads();
    for (int i = tid; i < T_STEPS * N1; i += 256) {
        int t = i / N1, n = i - t * N1;
        float s = 0.0f;
#pragma unroll
        for (int k = 0; k < 10; ++k)
            if (k <= t) s = fmaf(KV[k], h1s[(t - k) * N1 + n], s);
        p[i] = s;
    }
}

// ---------------------------------------------------------------------------
// Recurrent scan v5 (round-9 exact, best-known)
// ---------------------------------------------------------------------------
__global__ __launch_bounds__(512, 2) void snn_scan5(const float* __restrict__ syn2,
                                                    const unsigned short* __restrict__ W2pre2,
                                                    const float* __restrict__ W3,
                                                    float* __restrict__ out) {
    __shared__ __align__(16) unsigned short s2A[8192];   // [p][16][256]; rows 8..15 stay 0
    __shared__ __align__(16) float h2buf[8][132];
    __shared__ __align__(16) float s3buf[8][104];
    __shared__ __align__(16) float W3s[N3 * N2];
    __shared__ __align__(16) float pbuf[8][4][12];

    const int tid = threadIdx.x;
    const int wv  = tid >> 6;
    const int l   = tid & 63;
    const int m16 = l & 15;
    const int j2  = l >> 4;
    const int g   = wv;
    const int c   = l;
    const long b  = (long)blockIdx.x * 8 + g;

    for (int i = tid; i < N3 * N2; i += 512) W3s[i] = W3[i];
    for (int i = tid; i < 8192; i += 512) s2A[i] = 0;

    bf16x8 bh[7], bl[7];
    {
        const unsigned short* wp = W2pre2 + wv * 7168 + l * 8;
#pragma unroll
        for (int ks = 0; ks < 7; ++ks) {
            bh[ks] = *(const bf16x8*)(wp + ks * 1024);
            bl[ks] = *(const bf16x8*)(wp + ks * 1024 + 512);
        }
    }

    const int NL2 = (c < 8)  ? 4 : 3;
    const int NL3 = (c < 36) ? 2 : 1;
    const int o4  = c % 11;
    const int p4  = c / 11;
    const int kbeg = (p4 == 0) ? 0 : (4 + 24 * p4);
    const int nf4  = (p4 == 0) ? 7 : 6;

    float sl2h[10][4] = {}; float Ssl2[4] = {};
    float h2h[10][2]  = {}; float Dd3[2]  = {};
    float sl3h[10][2] = {}; float Ssl3[2] = {};
    float h3h[10]     = {}; float Dd4 = 0.f;
    float sl4h[10]    = {}; float Ssl4 = 0.f;
    float accum       = 0.0f;

    const float* syn2b = syn2 + b * (T_STEPS * N1);
    float syn_nxt[4];
#pragma unroll
    for (int jj = 0; jj < 4; ++jj) syn_nxt[jj] = (jj < NL2) ? syn2b[c + 64 * jj] : 0.0f;

    __syncthreads();

#pragma unroll 1
    for (int tb = 0; tb < T_STEPS; tb += 10) {
#pragma unroll
        for (int u = 0; u < 10; ++u) {
            const int t   = tb + u;
            const int um1 = (u + 9) % 10;
            const int um2 = (u + 8) % 10;
            const int um3 = (u + 7) % 10;
            const int um4 = (u + 6) % 10;
            const int um5 = (u + 5) % 10;

            float syn_cur[4];
#pragma unroll
            for (int jj = 0; jj < 4; ++jj) syn_cur[jj] = syn_nxt[jj];
            if (t + 1 < T_STEPS) {
#pragma unroll
                for (int jj = 0; jj < 4; ++jj)
                    if (jj < NL2) syn_nxt[jj] = syn2b[(t + 1) * N1 + c + 64 * jj];
            }

            // ---- P1: layer-2 (exact KS recurrence) ----
#pragma unroll
            for (int jj = 0; jj < 4; ++jj) {
                if (jj < NL2) {
                    const int n = c + 64 * jj;
                    const float slp = sl2h[um1][jj];
                    const float slo = sl2h[u][jj];          // lag 10
                    Ssl2[jj] = RHO * (Ssl2[jj] + slp) - RHO10 * slo;
                    const float mem2 = syn_cur[jj] - Ssl2[jj];
                    const float s2   = sigm10(mem2 - 0.5f);
                    sl2h[u][jj] = s2 * mem2;
                    unsigned short hi, lo; split2(s2, hi, lo);
                    const int off = g * 256 + (((n >> 3) ^ (g & 7)) * 8) + (n & 7);
                    s2A[off]        = hi;
                    s2A[4096 + off] = lo;
                }
            }
            __syncthreads();                               // bar 1

            // ---- P2: MFMA GEMM2 (2 independent chains) ----
            {
                f32x4 a0 = (f32x4){0.f, 0.f, 0.f, 0.f};
                f32x4 a1 = (f32x4){0.f, 0.f, 0.f, 0.f};
                const int swz = m16 & 7;
#pragma unroll
                for (int ks = 0; ks < 7; ++ks) {
                    const int gr = (4 * ks + j2) ^ swz;
                    const bf16x8 ahv = *(const bf16x8*)&s2A[m16 * 256 + gr * 8];
                    const bf16x8 alv = *(const bf16x8*)&s2A[4096 + m16 * 256 + gr * 8];
                    if (ks & 1) {
                        a1 = __builtin_amdgcn_mfma_f32_16x16x32_bf16(ahv, bh[ks], a1, 0, 0, 0);
                        a1 = __builtin_amdgcn_mfma_f32_16x16x32_bf16(alv, bh[ks], a1, 0, 0, 0);
                        a1 = __builtin_amdgcn_mfma_f32_16x16x32_bf16(ahv, bl[ks], a1, 0, 0, 0);
                    } else {
                        a0 = __builtin_amdgcn_mfma_f32_16x16x32_bf16(ahv, bh[ks], a0, 0, 0, 0);
                        a0 = __builtin_amdgcn_mfma_f32_16x16x32_bf16(alv, bh[ks], a0, 0, 0, 0);
                        a0 = __builtin_amdgcn_mfma_f32_16x16x32_bf16(ahv, bl[ks], a0, 0, 0, 0);
                    }
                }
                const f32x4 a = a0 + a1;
                if (j2 < 2) {
#pragma unroll
                    for (int q = 0; q < 4; ++q)
                        h2buf[j2 * 4 + q][wv * 16 + m16] = swishf(a[q]);
                }
            }
            __syncthreads();                               // bar 2

            // ---- P3: layer-3 ----
#pragma unroll
            for (int jj = 0; jj < 2; ++jj) {
                if (jj < NL3) {
                    const int m = c + 64 * jj;
                    const float hm = h2buf[g][m];
                    float gneg = C1 * h2h[um1][jj];
                    gneg = fmaf(C2, h2h[um2][jj], gneg);
                    gneg = fmaf(C3, h2h[um3][jj], gneg);
                    gneg = fmaf(C4, h2h[um4][jj], gneg);
                    Dd3[jj] = fmaf(RHO, Dd3[jj], h2h[um5][jj]);
                    Dd3[jj] = fmaf(-RHO5, h2h[u][jj], Dd3[jj]);
                    Ssl3[jj] = RHO * (Ssl3[jj] + sl3h[um1][jj]) - RHO10 * sl3h[u][jj];
                    const float mem3 = fmaf(KV0, hm, gneg) + Dd3[jj] - Ssl3[jj];
                    const float s3   = sigm10(mem3 - 0.5f);
                    sl3h[u][jj] = s3 * mem3;
                    h2h[u][jj]  = hm;
                    s3buf[g][m] = s3;
                }
            }
            asm volatile("s_waitcnt lgkmcnt(0)" ::: "memory");
            __builtin_amdgcn_sched_barrier(0);

            // ---- P4: GEMM3 partials (44 lanes) ----
            if (c < 44) {
                float part = 0.0f;
#pragma unroll
                for (int i = 0; i < 7; ++i) {
                    if (i < nf4) {
                        const float4 sv  = *(const float4*)&s3buf[g][kbeg + 4 * i];
                        const float4 wv4 = *(const float4*)&W3s[o4 * N2 + kbeg + 4 * i];
                        part = fmaf(sv.x, wv4.x, part);
                        part = fmaf(sv.y, wv4.y, part);
                        part = fmaf(sv.z, wv4.z, part);
                        part = fmaf(sv.w, wv4.w, part);
                    }
                }
                pbuf[g][p4][o4] = part;
            }
            asm volatile("s_waitcnt lgkmcnt(0)" ::: "memory");
            __builtin_amdgcn_sched_barrier(0);

            // ---- P5: layer-4 (11 lanes) ----
            if (c < N3) {
                const float a4 = pbuf[g][0][c] + pbuf[g][1][c] + pbuf[g][2][c] + pbuf[g][3][c];
                const float h3 = swishf(a4);
                float gneg = C1 * h3h[um1];
                gneg = fmaf(C2, h3h[um2], gneg);
                gneg = fmaf(C3, h3h[um3], gneg);
                gneg = fmaf(C4, h3h[um4], gneg);
                Dd4 = fmaf(RHO, Dd4, h3h[um5]);
                Dd4 = fmaf(-RHO5, h3h[u], Dd4);
                Ssl4 = RHO * (Ssl4 + sl4h[um1]) - RHO10 * sl4h[u];
                const float mem4 = fmaf(KV0, h3, gneg) + Dd4 - Ssl4;
                const float s4   = sigm10(mem4 - 0.5f);
                sl4h[u] = s4 * mem4;
                h3h[u]  = h3;
                accum += s4;
            }
        }
    }

    if (c < N3) out[b * N3 + c] = accum * 0.02f;
}

// ---------------------------------------------------------------------------
extern "C" void kernel_launch(void* const* d_in, const int* in_sizes, int n_in,
                              void* d_out, int out_size, void* d_ws, size_t ws_size,
                              hipStream_t stream) {
    const float* x  = (const float*)d_in[0];
    const float* W1 = (const float*)d_in[1];
    const float* W2 = (const float*)d_in[2];
    const float* W3 = (const float*)d_in[3];
    float* out = (float*)d_out;

    float* buf = (float*)d_ws;                                   // h1 -> syn2 in place
    unsigned short* W1pre  = (unsigned short*)(buf + (size_t)BATCH * T_STEPS * N1);
    unsigned short* W2pre2 = W1pre + 266240;

    prep_w<<<1264, 256, 0, stream>>>(W1, W2, W1pre, W2pre2);
    gemm1_mfma<<<1600, 512, 0, stream>>>(x, W1pre, buf);
    conv_k<<<BATCH, 256, 0, stream>>>(buf);
    snn_scan5<<<BATCH / 8, 512, 0, stream>>>(buf, W2pre2, W3, out);
}